// Round 5
// baseline (138.778 us; speedup 1.0000x reference)
//
#include <hip/hip_runtime.h>

// Problem constants
#define N_   8
#define C_   32
#define H_   256
#define W_   256
#define HW_  (H_ * W_)
#define BROW_ 132          // padded floats per (plane, k) block-row (129 used)
#define B_OFF_ 1024        // float offset of block array inside d_ws (ss first)

// pack 2-bit argmax pos into low mantissa bits of fp32 max (rel err 2^-22)
__device__ __forceinline__ float pack_vp(float m, int pos) {
    return __uint_as_float((__float_as_uint(m) & ~3u) | (unsigned)pos);
}

// ---------------------------------------------------------------------------
// Pass 1: per-(n,c) plane: instance-norm stats (-> scale/shift in ws[0..2KB))
//         AND per-2x2-block RAW max + argmax pos (scale>0 => raw order ==
//         normalized order, ties preserved), packed fp32 -> ws B array.
// Block j covers cols {2j-1, 2j}; j=0/128 store the real column's vertical
// max with its row bit (pad compare resolved in pass 2 post-normalize).
// grid = 256 planes, block = 1024 (16 waves). thread: k = t>>5, cols [8li,8li+8)
// ---------------------------------------------------------------------------
__global__ __launch_bounds__(1024) void pass1_kernel(
    const float* __restrict__ x, const float* __restrict__ gamma,
    const float* __restrict__ beta, float* __restrict__ ws)
{
    const int nc = blockIdx.x;
    const int t  = threadIdx.x;
    const int li = t & 31;
    const int k0 = t >> 5;
    const float* plane = x + (size_t)nc * HW_;
    float* Bp = ws + B_OFF_ + (size_t)nc * (128 * BROW_);

    float sx=0.f, sy=0.f, sz=0.f, sw=0.f;
    float qx=0.f, qy=0.f, qz=0.f, qw=0.f;

    #pragma unroll
    for (int p = 0; p < 4; ++p) {
        const int k = k0 + 32 * p;
        const float* r0 = plane + (size_t)(2 * k) * W_ + 8 * li;
        float4 a0 = ((const float4*)r0)[0];
        float4 a1 = ((const float4*)r0)[1];
        float4 b0 = ((const float4*)(r0 + W_))[0];
        float4 b1 = ((const float4*)(r0 + W_))[1];

        sx += a0.x + a1.x + b0.x + b1.x;
        sy += a0.y + a1.y + b0.y + b1.y;
        sz += a0.z + a1.z + b0.z + b1.z;
        sw += a0.w + a1.w + b0.w + b1.w;
        qx = fmaf(a0.x,a0.x,qx); qx = fmaf(a1.x,a1.x,qx);
        qx = fmaf(b0.x,b0.x,qx); qx = fmaf(b1.x,b1.x,qx);
        qy = fmaf(a0.y,a0.y,qy); qy = fmaf(a1.y,a1.y,qy);
        qy = fmaf(b0.y,b0.y,qy); qy = fmaf(b1.y,b1.y,qy);
        qz = fmaf(a0.z,a0.z,qz); qz = fmaf(a1.z,a1.z,qz);
        qz = fmaf(b0.z,b0.z,qz); qz = fmaf(b1.z,b1.z,qz);
        qw = fmaf(a0.w,a0.w,qw); qw = fmaf(a1.w,a1.w,qw);
        qw = fmaf(b0.w,b0.w,qw); qw = fmaf(b1.w,b1.w,qw);

        // vertical max per local col (tie -> row 0)
        float vm0 = fmaxf(a0.x, b0.x); int r0b = (b0.x > a0.x) ? 1 : 0;
        float vm1 = fmaxf(a0.y, b0.y); int r1b = (b0.y > a0.y) ? 1 : 0;
        float vm2 = fmaxf(a0.z, b0.z); int r2b = (b0.z > a0.z) ? 1 : 0;
        float vm3 = fmaxf(a0.w, b0.w); int r3b = (b0.w > a0.w) ? 1 : 0;
        float vm4 = fmaxf(a1.x, b1.x); int r4b = (b1.x > a1.x) ? 1 : 0;
        float vm5 = fmaxf(a1.y, b1.y); int r5b = (b1.y > a1.y) ? 1 : 0;
        float vm6 = fmaxf(a1.z, b1.z); int r6b = (b1.z > a1.z) ? 1 : 0;
        float vm7 = fmaxf(a1.w, b1.w); int r7b = (b1.w > a1.w) ? 1 : 0;

        // straddle: left col (8li-1) from previous lane (same k iff li>0)
        const float pvm = __shfl_up(vm7, 1);
        const int   pvr = __shfl_up(r7b, 1);

        float f0, f1, f2, f3;
        if (li == 0) {
            // block j=0: {left pad, col 0} -> store col0's vmax, pos=(row<<1)|1
            f0 = pack_vp(vm0, (r0b << 1) | 1);
        } else {
            bool cl = (pvm > vm0) || ((pvm == vm0) && (pvr <= r0b));
            f0 = cl ? pack_vp(pvm, pvr << 1) : pack_vp(vm0, (r0b << 1) | 1);
        }
        { bool cl = (vm1 > vm2) || ((vm1 == vm2) && (r1b <= r2b));
          f1 = cl ? pack_vp(vm1, r1b << 1) : pack_vp(vm2, (r2b << 1) | 1); }
        { bool cl = (vm3 > vm4) || ((vm3 == vm4) && (r3b <= r4b));
          f2 = cl ? pack_vp(vm3, r3b << 1) : pack_vp(vm4, (r4b << 1) | 1); }
        { bool cl = (vm5 > vm6) || ((vm5 == vm6) && (r5b <= r6b));
          f3 = cl ? pack_vp(vm5, r5b << 1) : pack_vp(vm6, (r6b << 1) | 1); }

        *(float4*)(Bp + (size_t)k * BROW_ + 4 * li) = make_float4(f0, f1, f2, f3);
        if (li == 31)   // block j=128: {col 255, right pad}
            Bp[(size_t)k * BROW_ + 128] = pack_vp(vm7, r7b << 1);
    }

    // stats reduce (16 waves)
    double s = (double)sx + (double)sy + (double)sz + (double)sw;
    double q = (double)qx + (double)qy + (double)qz + (double)qw;
    #pragma unroll
    for (int off = 32; off > 0; off >>= 1) {
        s += __shfl_down(s, off);
        q += __shfl_down(q, off);
    }
    __shared__ double rs[16], rq[16];
    const int wid = t >> 6;
    if ((t & 63) == 0) { rs[wid] = s; rq[wid] = q; }
    __syncthreads();
    if (t == 0) {
        double S = 0.0, Q = 0.0;
        #pragma unroll
        for (int i = 0; i < 16; ++i) { S += rs[i]; Q += rq[i]; }
        double mean = S / (double)HW_;
        double var  = Q / (double)HW_ - mean * mean;
        double grs  = (double)gamma[nc & (C_ - 1)] / sqrt(var + 1e-5);
        ((float2*)ws)[nc] = make_float2((float)grs,
                                        (float)((double)beta[nc & (C_ - 1)] - mean * grs));
    }
}

// ---------------------------------------------------------------------------
// Pass 2: block data -> normalize -> 0.75/0.25/0 rule -> 1x1 conv -> relu
// grid = (128 k, 4 qtr, 8 n), block = 256 (4 waves, wave owns an o-octet;
// lane owns ONE output column, both rows). LDS ~9.5 KB -> 8 wg/CU.
//   interior: val = vn>0 ? 0.75*vn : 0.25*vn    (vn = packed*scale+shift)
//   boundary (j=0 / j=128): val = vn>0 ? 0.75*vn : 0   (pad wins ties/negs)
// ---------------------------------------------------------------------------
__global__ __launch_bounds__(256, 8) void pass2_kernel(
    const float* __restrict__ ws, const float* __restrict__ Wm,
    const float* __restrict__ bias, float* __restrict__ out)
{
    const int k   = blockIdx.x;
    const int qtr = blockIdx.y;
    const int n   = blockIdx.z;
    const int t   = threadIdx.x;

    __shared__ float  sWT[C_][36];   // sWT[c][o] = W[o,c], padded stride
    __shared__ float  sB[C_][36];    // packed block vals, window j=32q..32q+35
    __shared__ float2 sSS[C_];

    #pragma unroll
    for (int r = 0; r < 4; ++r) {
        int i = t + (r << 8);
        sWT[i & 31][i >> 5] = Wm[i];
    }
    if (t < C_) sSS[t] = ((const float2*)ws)[n * C_ + t];

    const float4* B4 = (const float4*)(ws + B_OFF_);
    for (int i = t; i < 288; i += 256) {
        int c = i / 9, f = i - 9 * c;
        ((float4*)&sB[c][0])[f] =
            B4[(size_t)((n * C_ + c) * 128 + k) * 33 + qtr * 8 + f];
    }
    __syncthreads();

    const int wv  = t >> 6;
    const int ob  = wv << 3;
    const int Ll  = t & 63;                 // local out col; global L = 64*qtr+Ll
    const int jl  = (Ll + 1) >> 1;          // feeding block (window-local)
    const int pm0 = (Ll & 1) ? 0 : 1;       // row-0 match code
    const bool bnd = (qtr == 0 && Ll == 0) || (qtr == 3 && Ll == 63);
    const float negc = bnd ? 0.f : 0.25f;

    float acc0[8], acc1[8];
    #pragma unroll
    for (int oo = 0; oo < 8; ++oo) {
        float bo = bias[ob + oo];
        acc0[oo] = bo; acc1[oo] = bo;
    }

    #pragma unroll 8
    for (int cc = 0; cc < C_; ++cc) {
        float2 sc = sSS[cc];
        float pv  = sB[cc][jl];
        int  pos  = (int)(__float_as_uint(pv) & 3u);
        float vn  = fmaf(pv, sc.x, sc.y);
        float val = vn * ((vn > 0.f) ? 0.75f : negc);
        float m0  = (pos == pm0)     ? val : 0.f;
        float m1  = (pos == pm0 + 2) ? val : 0.f;
        float4 wa = *(const float4*)&sWT[cc][ob];
        float4 wb = *(const float4*)&sWT[cc][ob + 4];
        acc0[0] = fmaf(m0, wa.x, acc0[0]);
        acc0[1] = fmaf(m0, wa.y, acc0[1]);
        acc0[2] = fmaf(m0, wa.z, acc0[2]);
        acc0[3] = fmaf(m0, wa.w, acc0[3]);
        acc0[4] = fmaf(m0, wb.x, acc0[4]);
        acc0[5] = fmaf(m0, wb.y, acc0[5]);
        acc0[6] = fmaf(m0, wb.z, acc0[6]);
        acc0[7] = fmaf(m0, wb.w, acc0[7]);
        acc1[0] = fmaf(m1, wa.x, acc1[0]);
        acc1[1] = fmaf(m1, wa.y, acc1[1]);
        acc1[2] = fmaf(m1, wa.z, acc1[2]);
        acc1[3] = fmaf(m1, wa.w, acc1[3]);
        acc1[4] = fmaf(m1, wb.x, acc1[4]);
        acc1[5] = fmaf(m1, wb.y, acc1[5]);
        acc1[6] = fmaf(m1, wb.z, acc1[6]);
        acc1[7] = fmaf(m1, wb.w, acc1[7]);
    }

    float* obase = out + (size_t)(n * C_ + ob) * HW_
                       + (size_t)(2 * k) * W_ + (qtr << 6) + Ll;
    #pragma unroll
    for (int oo = 0; oo < 8; ++oo) {
        obase[(size_t)oo * HW_]      = fmaxf(acc0[oo], 0.f);
        obase[(size_t)oo * HW_ + W_] = fmaxf(acc1[oo], 0.f);
    }
}

extern "C" void kernel_launch(void* const* d_in, const int* in_sizes, int n_in,
                              void* d_out, int out_size, void* d_ws, size_t ws_size,
                              hipStream_t stream) {
    const float* x     = (const float*)d_in[0];
    const float* gamma = (const float*)d_in[1];
    const float* beta  = (const float*)d_in[2];
    const float* Wm    = (const float*)d_in[3];
    const float* bias  = (const float*)d_in[4];
    float* out = (float*)d_out;
    float* ws  = (float*)d_ws;   // [0,2KB): 256 x float2 scale/shift; B at +4KB

    pass1_kernel<<<N_ * C_, 1024, 0, stream>>>(x, gamma, beta, ws);
    pass2_kernel<<<dim3(H_ / 2, 4, N_), 256, 0, stream>>>(ws, Wm, bias, out);
}